// Round 14
// baseline (169.422 us; speedup 1.0000x reference)
//
#include <hip/hip_runtime.h>
#include <hip/hip_bf16.h>

#define N_ATOMS 512
#define CDIM 64
#define NSIG 16384
#define KS 4
#define NBINS 33
#define NS_BLK 8    // signals per block: 4 waves; GEMM wave=128 atoms, OMP half-wave=1 signal

// ws layout (floats): [0,32768) Dn[c][n] ; [32768,65536) DnT[n][c] ;
// [65536,327680) G[n][n] ; [327680,344064) per-signal loss partials
#define WS_DN   0
#define WS_DNT  32768
#define WS_G    65536
#define WS_PART 327680

// Hs column swizzle: F(n) = n ^ (((n>>5)&7)<<2). Identity on bits 0-1 (keeps
// float2/float4 contiguity), flips bits 2-4. For 32-lane/16-atom b128 reads
// plus the +4-bank row stagger (stride 516), every wave64 b128 op lands 8
// lanes per bank-quad — the b128 optimum.
__device__ __forceinline__ int swz(int n) { return n ^ (((n >> 5) & 7) << 2); }

__global__ void k_normalize(const float* __restrict__ dict,
                            float* __restrict__ Dn, float* __restrict__ DnT) {
    const int n = blockIdx.x;    // atom/column
    const int c = threadIdx.x;   // channel/row (64 threads = 1 wave)
    float v = dict[c * N_ATOMS + n];
    float sq = v * v;
    #pragma unroll
    for (int off = 32; off > 0; off >>= 1) sq += __shfl_down(sq, off);
    sq = __shfl(sq, 0);
    float m = fmaxf(sqrtf(sq), 1e-10f);
    float r = v / m;             // division to match reference exactly
    Dn[c * N_ATOMS + n] = r;
    DnT[n * CDIM + c]  = r;
}

__global__ void k_gram(const float* __restrict__ Dn, float* __restrict__ G) {
    __shared__ float sc[CDIM];
    const int i = blockIdx.x;
    const int t = threadIdx.x;
    if (t < CDIM) sc[t] = Dn[t * N_ATOMS + i];
    __syncthreads();
    for (int j = t; j < N_ATOMS; j += 256) {
        float a = 0.f;
        #pragma unroll
        for (int c = 0; c < CDIM; c++) a = fmaf(sc[c], Dn[c * N_ATOMS + j], a);
        G[i * N_ATOMS + j] = a;
    }
}

// Fused v6: GEMM -> swizzled LDS h_bar -> half-wave OMP (2 signals/wave in
// parallel) -> wave-per-signal epilogue.
__global__ __launch_bounds__(256, 8) void k_fused5(
    const float* __restrict__ z, const float* __restrict__ Dn,
    const float* __restrict__ DnT, const float* __restrict__ G,
    float* __restrict__ part, float* __restrict__ out)
{
    __shared__ float Xs[CDIM][NS_BLK];   // [c][s] 2 KB (rows 32B-aligned)
    __shared__ float Hs[NS_BLK][516];    // swizzled hbar 16.5 KB; later zste overlay
    __shared__ float cqA[NS_BLK][4];
    __shared__ int   IA[NS_BLK][4];
    __shared__ float tkA[NS_BLK][4];
    const int t = threadIdx.x;
    const int wave = t >> 6, lane = t & 63;
    const int s0 = blockIdx.x * NS_BLK;
    const int b = s0 >> 10;
    const int hw0 = s0 & 1023;

    if (t < 128) {   // coalesced z stage: c = t>>1, signals f..f+3
        const int c = t >> 1, f = (t & 1) * 4;
        float4 v = *(const float4*)(z + (b * CDIM + c) * 1024 + hw0 + f);
        *(float4*)(&Xs[c][f]) = v;
    }
    __syncthreads();

    {   // GEMM: wave owns atoms [wave*128,+128), lane owns 2 (k-ascending fmaf,
        // bit-identical to all prior rounds). Store to swizzled columns.
        const int n0 = wave * 128 + lane * 2;
        const int col0 = swz(n0);        // bits 0-1 preserved -> pair contiguous
        float acc[NS_BLK][2];
        #pragma unroll
        for (int q = 0; q < NS_BLK; q++) { acc[q][0] = 0.f; acc[q][1] = 0.f; }
        for (int k = 0; k < CDIM; k++) {
            const float2 d = *(const float2*)(Dn + k * N_ATOMS + n0);
            float4 xlo = *(const float4*)(&Xs[k][0]);
            float4 xhi = *(const float4*)(&Xs[k][4]);
            const float xs[NS_BLK] = {xlo.x, xlo.y, xlo.z, xlo.w,
                                      xhi.x, xhi.y, xhi.z, xhi.w};
            #pragma unroll
            for (int q = 0; q < NS_BLK; q++) {
                acc[q][0] = fmaf(xs[q], d.x, acc[q][0]);
                acc[q][1] = fmaf(xs[q], d.y, acc[q][1]);
            }
        }
        #pragma unroll
        for (int q = 0; q < NS_BLK; q++)
            *(float2*)(&Hs[q][col0]) = make_float2(acc[q][0], acc[q][1]);
    }
    __syncthreads();

    // ---- OMP: half-wave (32 lanes) = 1 signal; lane owns 16 atoms ----
    const int half = lane >> 5, hl = lane & 31;
    const int sl = wave * 2 + half;
    const float* hrow = &Hs[sl][0];

    float ha[16];   // masked |h| (sign never used; selected entries exact 0)
    #pragma unroll
    for (int j4 = 0; j4 < 4; j4++) {
        float4 hv = *(const float4*)(hrow + swz(hl * 16 + j4 * 4));
        ha[j4 * 4 + 0] = fabsf(hv.x); ha[j4 * 4 + 1] = fabsf(hv.y);
        ha[j4 * 4 + 2] = fabsf(hv.z); ha[j4 * 4 + 3] = fabsf(hv.w);
    }

    unsigned sel = 0;
    int I[KS]; float coef[KS];
    float L[KS][KS]; float hsel[KS]; float inv[KS];
    L[0][0] = 1.f; inv[0] = 1.f;

    #pragma unroll
    for (int k = 0; k < KS; k++) {
        // max over the signal's 512 masked |h| (selected are exact 0 == where())
        float m0 = fmaxf(fmaxf(fmaxf(ha[0], ha[1]), fmaxf(ha[2], ha[3])),
                         fmaxf(fmaxf(ha[4], ha[5]), fmaxf(ha[6], ha[7])));
        float m1 = fmaxf(fmaxf(fmaxf(ha[8], ha[9]), fmaxf(ha[10], ha[11])),
                         fmaxf(fmaxf(ha[12], ha[13]), fmaxf(ha[14], ha[15])));
        float mv = fmaxf(m0, m1);
        #pragma unroll
        for (int off = 1; off <= 16; off <<= 1)   // 32-lane butterfly (stays in half)
            mv = fmaxf(mv, __shfl_xor(mv, off));
        // lowest atom index attaining mv (exact equality == first-max tie-break)
        int cand = 2048;
        #pragma unroll
        for (int j = 15; j >= 0; j--)
            if (ha[j] == mv) cand = hl * 16 + j;
        unsigned long long mk = __ballot(cand < 2048);
        const unsigned mh = (unsigned)(mk >> (half * 32));
        const int lo = (int)__builtin_ctz(mh);
        const int idx = __shfl(cand, half * 32 + lo);
        if ((idx >> 4) == hl) sel |= 1u << (idx & 15);

        if (k > 0) {
            float w[KS - 1];
            for (int i2 = 0; i2 < k; i2++) {
                float tt = G[I[i2] * N_ATOMS + idx];   // half-uniform scalar load
                for (int j2 = 0; j2 < i2; j2++) tt -= L[i2][j2] * w[j2];
                w[i2] = tt * inv[i2];
            }
            float ssum = 0.f;
            for (int j2 = 0; j2 < k; j2++) ssum += w[j2] * w[j2];
            float corner = sqrtf(fmaxf(1.f - ssum, 1e-12f));
            for (int j2 = 0; j2 < k; j2++) L[k][j2] = w[j2];
            L[k][k] = corner;
            inv[k] = 1.f / corner;
        }
        I[k] = idx;
        hsel[k] = hrow[swz(idx)];     // h_bar[idx], same bits

        float y[KS];
        for (int i2 = 0; i2 <= k; i2++) {
            float tt = hsel[i2];
            for (int j2 = 0; j2 < i2; j2++) tt -= L[i2][j2] * y[j2];
            y[i2] = tt * inv[i2];
        }
        for (int i2 = k; i2 >= 0; i2--) {
            float tt = y[i2];
            for (int j2 = i2 + 1; j2 <= k; j2++) tt -= L[j2][i2] * coef[j2];
            coef[i2] = tt * inv[i2];
        }

        // h = h_bar - x @ G (lane's 16 atoms; m-ascending fmaf per element —
        // same arithmetic order as prior rounds; j4-blocking is layout only)
        if (k < KS - 1) {
            #pragma unroll
            for (int j4 = 0; j4 < 4; j4++) {
                float4 av = make_float4(0.f, 0.f, 0.f, 0.f);
                for (int m = 0; m <= k; m++) {
                    float4 gv = *(const float4*)(G + I[m] * N_ATOMS + hl * 16 + j4 * 4);
                    const float cm = coef[m];
                    av.x = fmaf(cm, gv.x, av.x); av.y = fmaf(cm, gv.y, av.y);
                    av.z = fmaf(cm, gv.z, av.z); av.w = fmaf(cm, gv.w, av.w);
                }
                float4 hbv = *(const float4*)(hrow + swz(hl * 16 + j4 * 4));
                ha[j4 * 4 + 0] = ((sel >> (j4 * 4 + 0)) & 1) ? 0.f : fabsf(hbv.x - av.x);
                ha[j4 * 4 + 1] = ((sel >> (j4 * 4 + 1)) & 1) ? 0.f : fabsf(hbv.y - av.y);
                ha[j4 * 4 + 2] = ((sel >> (j4 * 4 + 2)) & 1) ? 0.f : fabsf(hbv.z - av.z);
                ha[j4 * 4 + 3] = ((sel >> (j4 * 4 + 3)) & 1) ? 0.f : fabsf(hbv.w - av.w);
            }
        }
    }

    if (hl == 0) {   // lanes 0 and 32: quantize + publish their signal
        #pragma unroll
        for (int j = 0; j < KS; j++) {
            float c2 = fminf(fmaxf(coef[j], -2.f), 2.f);
            float bf = (c2 + 2.f) / 4.f * 32.f;
            int bin = (int)rintf(bf);
            bin = bin < 0 ? 0 : (bin > 32 ? 32 : bin);
            cqA[sl][j] = -2.f + 0.125f * (float)bin;
            IA[sl][j]  = I[j];
            tkA[sl][j] = (float)(I[j] * NBINS + bin);
        }
    }
    __syncthreads();

    // ---- epilogue: wave = 1 signal (64 channels), 2 rounds ----
    #pragma unroll
    for (int r = 0; r < 2; r++) {
        const int sl2 = r * 4 + wave;
        const int s = s0 + sl2;
        const float xch = Xs[lane][sl2];
        float zq = 0.f;
        #pragma unroll
        for (int j = 0; j < KS; j++)
            zq = fmaf(cqA[sl2][j], DnT[IA[sl2][j] * CDIM + lane], zq);
        float diff = zq - xch;
        Hs[sl2][lane] = xch + (zq - xch);   // zste overlay (all OMP reads done)
        float sq = diff * diff;
        #pragma unroll
        for (int off = 32; off > 0; off >>= 1) sq += __shfl_down(sq, off);
        if (lane == 0) part[s] = sq;
    }
    __syncthreads();

    if (t < 128) {   // coalesced zste write: c = t>>1, signals f..f+3
        const int c = t >> 1, f = (t & 1) * 4;
        float4 v;
        v.x = Hs[f + 0][c]; v.y = Hs[f + 1][c];
        v.z = Hs[f + 2][c]; v.w = Hs[f + 3][c];
        *(float4*)(out + (b * CDIM + c) * 1024 + hw0 + f) = v;
    }
    if (t < NS_BLK * KS)   // 32 consecutive token floats
        out[NSIG * CDIM + 1 + s0 * KS + t] = tkA[t >> 2][t & 3];
}

__global__ __launch_bounds__(256) void k_final(const float* __restrict__ part,
                                               float* __restrict__ out) {
    __shared__ float red[4];
    const int t = threadIdx.x;
    float sum = 0.f;
    const float4* p4 = (const float4*)part;
    for (int i = t; i < NSIG / 4; i += 256) {
        float4 v = p4[i];
        sum += v.x + v.y + v.z + v.w;
    }
    #pragma unroll
    for (int off = 32; off > 0; off >>= 1) sum += __shfl_down(sum, off);
    if ((t & 63) == 0) red[t >> 6] = sum;
    __syncthreads();
    if (t == 0) {
        float v = (red[0] + red[1] + red[2] + red[3]) / 1048576.f;
        out[NSIG * CDIM] = v + 0.25f * v;
    }
}

extern "C" void kernel_launch(void* const* d_in, const int* in_sizes, int n_in,
                              void* d_out, int out_size, void* d_ws, size_t ws_size,
                              hipStream_t stream) {
    const float* z    = (const float*)d_in[0];
    const float* dict = (const float*)d_in[1];
    float* out  = (float*)d_out;
    float* w    = (float*)d_ws;
    float* Dn   = w + WS_DN;
    float* DnT  = w + WS_DNT;
    float* G    = w + WS_G;
    float* part = w + WS_PART;

    hipLaunchKernelGGL(k_normalize, dim3(N_ATOMS), dim3(CDIM), 0, stream, dict, Dn, DnT);
    hipLaunchKernelGGL(k_gram,      dim3(N_ATOMS), dim3(256),  0, stream, Dn, G);
    hipLaunchKernelGGL(k_fused5,    dim3(NSIG / NS_BLK), dim3(256), 0, stream,
                       z, Dn, DnT, G, part, out);
    hipLaunchKernelGGL(k_final,     dim3(1), dim3(256), 0, stream, part, out);
}